// Round 8
// baseline (291.652 us; speedup 1.0000x reference)
//
#include <hip/hip_runtime.h>
#include <hip/hip_bf16.h>

#define BATCH 2
#define SEQ   2048
#define DIM   1024
#define NH    16
#define HD    64
#define K_DIM 1024

typedef __attribute__((ext_vector_type(8))) short short8;
typedef __attribute__((ext_vector_type(4))) short short4v;
typedef __attribute__((ext_vector_type(4))) float f32x4;
typedef unsigned short ushort_t;

// fp32 -> bf16 bits, round-to-nearest-even
__device__ __forceinline__ unsigned short f2b(float x) {
    unsigned int u = __float_as_uint(x);
    u += 0x7FFFu + ((u >> 16) & 1u);
    return (unsigned short)(u >> 16);
}

// async global->LDS, 16B per lane; LDS dest = wave-uniform base + lane*16
#define ASYNC_COPY16(gp, lp) \
    __builtin_amdgcn_global_load_lds((const __attribute__((address_space(1))) void*)(gp), \
                                     (__attribute__((address_space(3))) void*)(lp), 16, 0, 0)

// ---------------------------------------------------------------------------
// Merged prep kernel: [0,1024) cast x; [1024,2560) transpose w_qkv;
// [2560,3072) transpose w_out.
// ---------------------------------------------------------------------------
__global__ __launch_bounds__(256)
void prep(const float* __restrict__ x, const float* __restrict__ w_qkv,
          const float* __restrict__ w_out, ushort_t* __restrict__ xb,
          ushort_t* __restrict__ wqb, ushort_t* __restrict__ wob)
{
    const int bid = blockIdx.x;
    if (bid < 1024) {
        constexpr int n4 = (BATCH * SEQ * DIM) / 4;
        int i = bid * 256 + threadIdx.x;
        for (; i < n4; i += 1024 * 256) {
            float4 v = ((const float4*)x)[i];
            short4v o;
            o[0] = (short)f2b(v.x); o[1] = (short)f2b(v.y);
            o[2] = (short)f2b(v.z); o[3] = (short)f2b(v.w);
            ((short4v*)xb)[i] = o;
        }
    } else {
        const int lane = threadIdx.x & 63;
        const float* src; ushort_t* dst; int N, job;
        if (bid < 2560) { src = w_qkv; dst = wqb; N = 3072; job = (bid - 1024) * 4 + (threadIdx.x >> 6); }
        else            { src = w_out; dst = wob; N = 1024; job = (bid - 2560) * 4 + (threadIdx.x >> 6); }
        const int jn = (N == 3072) ? (job % 48) : (job % 16);
        const int jk = (N == 3072) ? (job / 48) : (job / 16);
        const int n  = jn * 64 + lane;
        const int k0 = jk * 8;
        short8 o;
        #pragma unroll
        for (int j = 0; j < 8; ++j) o[j] = (short)f2b(src[(size_t)(k0 + j) * N + n]);
        *(short8*)(dst + (size_t)n * K_DIM + k0) = o;
    }
}

// ---------------------------------------------------------------------------
// MFMA GEMM mainloop: BK=32, double-buffered LDS, post-barrier prefetch.
// ---------------------------------------------------------------------------
__device__ __forceinline__ void gemm_stage(const ushort_t* __restrict__ Ag,
                                           const ushort_t* __restrict__ Bg,
                                           ushort_t* As, ushort_t* Bs,
                                           int k0, int w, int r0, int c0)
{
    ASYNC_COPY16(Ag + (size_t)r0 * K_DIM + k0 + c0 * 8,        As + w * 512);
    ASYNC_COPY16(Ag + (size_t)(64 + r0) * K_DIM + k0 + c0 * 8, As + w * 512 + 2048);
    ASYNC_COPY16(Bg + (size_t)r0 * K_DIM + k0 + c0 * 8,        Bs + w * 512);
    ASYNC_COPY16(Bg + (size_t)(64 + r0) * K_DIM + k0 + c0 * 8, Bs + w * 512 + 2048);
}

__device__ __forceinline__ void mfma_gemm_tile(
    const ushort_t* __restrict__ Ag, const ushort_t* __restrict__ Bg,
    ushort_t (&As)[2][128 * 32], ushort_t (&Bs)[2][128 * 32], f32x4 acc[4][4])
{
    const int t = threadIdx.x;
    const int w = t >> 6, lane = t & 63;
    const int qd = lane >> 4, cl = lane & 15;
    const int p0 = w * 64 + lane;
    const int r0 = p0 >> 2;
    const int c0 = (p0 & 3) ^ (r0 & 3);

    gemm_stage(Ag, Bg, As[0], Bs[0], 0, w, r0, c0);

    for (int kt = 0; kt < K_DIM / 32; ++kt) {
        const int cur = kt & 1;
        __syncthreads();
        if (kt + 1 < K_DIM / 32)
            gemm_stage(Ag, Bg, As[cur ^ 1], Bs[cur ^ 1], (kt + 1) * 32, w, r0, c0);

        short8 af[4], bfr[4];
        #pragma unroll
        for (int rt = 0; rt < 4; ++rt) {
            const int row = (w >> 1) * 64 + rt * 16 + cl;
            af[rt] = *(const short8*)(As[cur] + row * 32 + ((qd ^ (row & 3)) * 8));
        }
        #pragma unroll
        for (int ct = 0; ct < 4; ++ct) {
            const int col = (w & 1) * 64 + ct * 16 + cl;
            bfr[ct] = *(const short8*)(Bs[cur] + col * 32 + ((qd ^ (col & 3)) * 8));
        }
        #pragma unroll
        for (int rt = 0; rt < 4; ++rt)
            #pragma unroll
            for (int ct = 0; ct < 4; ++ct)
                acc[rt][ct] = __builtin_amdgcn_mfma_f32_16x16x32_bf16(
                    af[rt], bfr[ct], acc[rt][ct], 0, 0, 0);
    }
}

// ---------------------------------------------------------------------------
// GEMM1: qkv = xb @ wqb^T with fused RoPE + bf16 stores.
// ---------------------------------------------------------------------------
__global__ __launch_bounds__(256, 3)
void gemm_qkv_mfma(const ushort_t* __restrict__ xb, const ushort_t* __restrict__ wqb,
                   ushort_t* __restrict__ qb, ushort_t* __restrict__ kb,
                   ushort_t* __restrict__ vt,
                   const float* __restrict__ cosb, const float* __restrict__ sinb)
{
    __shared__ __align__(16) ushort_t As[2][128 * 32];
    __shared__ __align__(16) ushort_t Bs[2][128 * 32];
    const int m0 = blockIdx.y * 128, n0 = blockIdx.x * 128;

    f32x4 acc[4][4];
    #pragma unroll
    for (int i = 0; i < 4; ++i)
        #pragma unroll
        for (int j = 0; j < 4; ++j)
            #pragma unroll
            for (int r = 0; r < 4; ++r) acc[i][j][r] = 0.f;

    mfma_gemm_tile(xb + (size_t)m0 * K_DIM, wqb + (size_t)n0 * K_DIM, As, Bs, acc);

    const int t = threadIdx.x, w = t >> 6, lane = t & 63;
    const int qd = lane >> 4, cl = lane & 15;
    const int b = m0 >> 11;
    const int lbase = (m0 & 2047) + (w >> 1) * 64;
    const int region = blockIdx.x >> 3;              // 0=q, 1=k, 2=v
    const int h = (blockIdx.x & 7) * 2 + (w & 1);

    if (region < 2) {
        ushort_t* dst = region ? kb : qb;
        const float sc = region ? 1.0f : 0.18033688011111234f;  // 0.125*log2(e)
        #pragma unroll
        for (int rt = 0; rt < 4; ++rt) {
            #pragma unroll
            for (int r = 0; r < 4; ++r) {
                const int l = lbase + rt * 16 + qd * 4 + r;
                const float c0 = cosb[l * HD + cl],      s0 = sinb[l * HD + cl];
                const float c1 = cosb[l * HD + 16 + cl], s1 = sinb[l * HD + 16 + cl];
                const float v0 = acc[rt][0][r] * c0 - acc[rt][2][r] * s0;
                const float v1 = acc[rt][1][r] * c1 - acc[rt][3][r] * s1;
                const float v2 = acc[rt][2][r] * c0 + acc[rt][0][r] * s0;
                const float v3 = acc[rt][3][r] * c1 + acc[rt][1][r] * s1;
                ushort_t* p = dst + (((size_t)b * NH + h) * SEQ + l) * HD;
                p[cl]      = f2b(v0 * sc);
                p[16 + cl] = f2b(v1 * sc);
                p[32 + cl] = f2b(v2 * sc);
                p[48 + cl] = f2b(v3 * sc);
            }
        }
    } else {
        #pragma unroll
        for (int rt = 0; rt < 4; ++rt)
            #pragma unroll
            for (int ct = 0; ct < 4; ++ct) {
                const int d = ct * 16 + cl;
                const int l = lbase + rt * 16 + qd * 4;
                short4v o4;
                #pragma unroll
                for (int r = 0; r < 4; ++r) o4[r] = (short)f2b(acc[rt][ct][r]);
                *(short4v*)(vt + (((size_t)b * NH + h) * HD + d) * SEQ + l) = o4;
            }
    }
}

// ---------------------------------------------------------------------------
// GEMM2: out = ob @ wob^T, fp32 store.
// ---------------------------------------------------------------------------
__global__ __launch_bounds__(256, 3)
void gemm_out_mfma(const ushort_t* __restrict__ ob, const ushort_t* __restrict__ wob,
                   float* __restrict__ out)
{
    __shared__ __align__(16) ushort_t As[2][128 * 32];
    __shared__ __align__(16) ushort_t Bs[2][128 * 32];
    const int m0 = blockIdx.y * 128, n0 = blockIdx.x * 128;

    f32x4 acc[4][4];
    #pragma unroll
    for (int i = 0; i < 4; ++i)
        #pragma unroll
        for (int j = 0; j < 4; ++j)
            #pragma unroll
            for (int r = 0; r < 4; ++r) acc[i][j][r] = 0.f;

    mfma_gemm_tile(ob + (size_t)m0 * K_DIM, wob + (size_t)n0 * K_DIM, As, Bs, acc);

    const int t = threadIdx.x, w = t >> 6, lane = t & 63;
    const int qd = lane >> 4, cl = lane & 15;
    const int mbase = m0 + (w >> 1) * 64, nbase = n0 + (w & 1) * 64;
    #pragma unroll
    for (int rt = 0; rt < 4; ++rt)
        #pragma unroll
        for (int ct = 0; ct < 4; ++ct)
            #pragma unroll
            for (int r = 0; r < 4; ++r)
                out[(size_t)(mbase + rt * 16 + qd * 4 + r) * DIM + nbase + ct * 16 + cl] =
                    acc[rt][ct][r];
}

// ---------------------------------------------------------------------------
// Flash attention v6: split-K x2, XCD-local grid, single-buffered K/V LDS
// (32KB -> 4 blocks/CU with the 64/64 VGPR/AGPR budget), REGISTER-LEAN:
// no PV-deferral, kh-split kf/pf reads. Per iter: barrier (stage kt drained)
// -> S-MFMAs (kf kh-split) -> vf reads -> barrier -> stage kt+1 -> exp/pack/P
// -> PV. Occupancy covers the exp->PV chain.
// ---------------------------------------------------------------------------
__global__ __launch_bounds__(256, 4)
void attn_mfma(const ushort_t* __restrict__ qb, const ushort_t* __restrict__ kb,
               const ushort_t* __restrict__ vt, float* __restrict__ Op,
               float* __restrict__ lp)
{
    const int h = blockIdx.x;                 // fastest -> K/V sharers on one XCD
    const int b = blockIdx.y >> 1;
    const int half = blockIdx.y & 1;
    const int qt = blockIdx.z;
    const int t = threadIdx.x;
    const int w = t >> 6, lane = t & 63;
    const int qd = lane >> 4, cl = lane & 15;
    constexpr int NT = SEQ / 64 / 2;          // 16 tiles per half

    __shared__ __align__(16) ushort_t Ks[64 * 64];   // 8KB, single buffer
    __shared__ __align__(16) ushort_t Vs[64 * 64];   // 8KB
    __shared__ __align__(16) ushort_t P[4][2048];    // 16KB
    char* Pb = (char*)P[w];

    const size_t bh = (size_t)b * NH + h;
    const ushort_t* qbase = qb + (bh * SEQ + qt * 128 + w * 32) * HD;
    const ushort_t* kbase = kb + bh * SEQ * HD;
    const ushort_t* vbase = vt + bh * (size_t)HD * SEQ;

    const int p0 = w * 128 + lane;
    const int r0a = p0 >> 3,  c0a = (p0 & 7) ^ (r0a & 7);
    const int p1 = p0 + 64;
    const int r1a = p1 >> 3,  c1a = (p1 & 7) ^ (r1a & 7);
    const int ldsoff0 = (w * 128) * 8;
    const int ldsoff1 = (w * 128 + 64) * 8;

    short8 qf[2][2];
    #pragma unroll
    for (int nt = 0; nt < 2; ++nt)
        #pragma unroll
        for (int kh = 0; kh < 2; ++kh)
            qf[nt][kh] = *(const short8*)(qbase + (nt * 16 + cl) * HD + kh * 32 + qd * 8);

    f32x4 oaccT[4][2];
    float l_part[2] = {0.f, 0.f};
    #pragma unroll
    for (int dt = 0; dt < 4; ++dt)
        #pragma unroll
        for (int nt = 0; nt < 2; ++nt)
            #pragma unroll
            for (int r = 0; r < 4; ++r) oaccT[dt][nt][r] = 0.f;

    const int g0 = half * NT;
    {   // stage first tile
        ASYNC_COPY16(kbase + (size_t)(g0 * 64 + r0a) * HD + c0a * 8, Ks + ldsoff0);
        ASYNC_COPY16(kbase + (size_t)(g0 * 64 + r1a) * HD + c1a * 8, Ks + ldsoff1);
        ASYNC_COPY16(vbase + (size_t)r0a * SEQ + g0 * 64 + c0a * 8,  Vs + ldsoff0);
        ASYNC_COPY16(vbase + (size_t)r1a * SEQ + g0 * 64 + c1a * 8,  Vs + ldsoff1);
    }

    for (int kt = 0; kt < NT; ++kt) {
        __syncthreads();   // stage(kt) drained into Ks/Vs

        // ---- S^T = K Q^T, kf kh-split to cap live registers at kf[4]
        f32x4 s[4][2];
        #pragma unroll
        for (int mt = 0; mt < 4; ++mt)
            #pragma unroll
            for (int nt = 0; nt < 2; ++nt)
                #pragma unroll
                for (int r = 0; r < 4; ++r) s[mt][nt][r] = 0.f;
        #pragma unroll
        for (int kh = 0; kh < 2; ++kh) {
            short8 kf[4];
            #pragma unroll
            for (int mt = 0; mt < 4; ++mt)
                kf[mt] = *(const short8*)(Ks + ((mt * 16 + cl) * 8 + ((kh * 4 + qd) ^ (cl & 7))) * 8);
            #pragma unroll
            for (int mt = 0; mt < 4; ++mt)
                #pragma unroll
                for (int nt = 0; nt < 2; ++nt)
                    s[mt][nt] = __builtin_amdgcn_mfma_f32_16x16x32_bf16(
                        kf[mt], qf[nt][kh], s[mt][nt], 0, 0, 0);
        }

        // ---- V fragments (live through exp; K data now consumed)
        short8 vf[4][2];
        #pragma unroll
        for (int dt = 0; dt < 4; ++dt)
            #pragma unroll
            for (int kh = 0; kh < 2; ++kh)
                vf[dt][kh] = *(const short8*)(Vs + ((dt * 16 + cl) * 8 + ((kh * 4 + qd) ^ (cl & 7))) * 8);

        __syncthreads();   // all waves done reading Ks/Vs

        if (kt + 1 < NT) {
            const int g = g0 + kt + 1;
            ASYNC_COPY16(kbase + (size_t)(g * 64 + r0a) * HD + c0a * 8, Ks + ldsoff0);
            ASYNC_COPY16(kbase + (size_t)(g * 64 + r1a) * HD + c1a * 8, Ks + ldsoff1);
            ASYNC_COPY16(vbase + (size_t)r0a * SEQ + g * 64 + c0a * 8,  Vs + ldsoff0);
            ASYNC_COPY16(vbase + (size_t)r1a * SEQ + g * 64 + c1a * 8,  Vs + ldsoff1);
        }

        // ---- exp2 + pack + P^T write
        #pragma unroll
        for (int nt = 0; nt < 2; ++nt) {
            #pragma unroll
            for (int mt = 0; mt < 4; ++mt) {
                const float e0 = __builtin_amdgcn_exp2f(s[mt][nt][0]);
                const float e1 = __builtin_amdgcn_exp2f(s[mt][nt][1]);
                const float e2 = __builtin_amdgcn_exp2f(s[mt][nt][2]);
                const float e3 = __builtin_amdgcn_exp2f(s[mt][nt][3]);
                l_part[nt] += (e0 + e1) + (e2 + e3);
                union { __hip_bfloat162 h2[2]; unsigned long long u64; } pk;
                pk.h2[0] = __float22bfloat162_rn(make_float2(e0, e1));
                pk.h2[1] = __float22bfloat162_rn(make_float2(e2, e3));
                const int g = (mt * 2 + (qd >> 1)) ^ (cl & 7);
                *(unsigned long long*)(Pb + (nt * 16 + cl) * 128 + g * 16 + (qd & 1) * 8) = pk.u64;
            }
        }
        __builtin_amdgcn_wave_barrier();

        // ---- O^T += V^T P^T, pf kh-split
        #pragma unroll
        for (int kh = 0; kh < 2; ++kh) {
            short8 pf[2];
            #pragma unroll
            for (int nt = 0; nt < 2; ++nt)
                pf[nt] = *(const short8*)(Pb + (nt * 16 + cl) * 128 + (((kh * 4 + qd) ^ (cl & 7)) * 16));
            #pragma unroll
            for (int dt = 0; dt < 4; ++dt)
                #pragma unroll
                for (int nt = 0; nt < 2; ++nt)
                    oaccT[dt][nt] = __builtin_amdgcn_mfma_f32_16x16x32_bf16(
                        vf[dt][kh], pf[nt], oaccT[dt][nt], 0, 0, 0);
        }
        __builtin_amdgcn_wave_barrier();   // P reads before next iter's writes
    }

    // ---- epilogue: fp32 partials
    #pragma unroll
    for (int nt = 0; nt < 2; ++nt) {
        float l = l_part[nt];
        l += __shfl_xor(l, 16);
        l += __shfl_xor(l, 32);
        const int query = qt * 128 + w * 32 + nt * 16 + cl;
        if (qd == 0)
            lp[((size_t)half * BATCH + b) * NH * SEQ + (size_t)h * SEQ + query] = l;
        float* op = Op + (((size_t)half * BATCH + b) * SEQ + query) * DIM + h * HD;
        #pragma unroll
        for (int dt = 0; dt < 4; ++dt)
            *(f32x4*)(op + dt * 16 + qd * 4) = oaccT[dt][nt];
    }
}

// ---------------------------------------------------------------------------
// Combine split-K halves: ob = (Op0+Op1)/(lp0+lp1), bf16.
// ---------------------------------------------------------------------------
__global__ __launch_bounds__(256)
void reduce_o(const float* __restrict__ Op, const float* __restrict__ lp,
              ushort_t* __restrict__ ob)
{
    const int idx = blockIdx.x * 256 + threadIdx.x;
    const int d4 = idx & 255;
    const int l  = (idx >> 8) & 2047;
    const int b  = idx >> 19;
    const int h  = d4 >> 4;

    const size_t o_off = ((size_t)b * SEQ + l) * DIM + d4 * 4;
    const float4 a = *(const float4*)(Op + o_off);
    const float4 c = *(const float4*)(Op + (size_t)BATCH * SEQ * DIM + o_off);
    const size_t l_off = ((size_t)b * NH + h) * SEQ + l;
    const float inv = 1.0f / (lp[l_off] + lp[(size_t)BATCH * NH * SEQ + l_off]);

    short4v o4;
    o4[0] = (short)f2b((a.x + c.x) * inv);
    o4[1] = (short)f2b((a.y + c.y) * inv);
    o4[2] = (short)f2b((a.z + c.z) * inv);
    o4[3] = (short)f2b((a.w + c.w) * inv);
    *(short4v*)(ob + o_off) = o4;
}

// ---------------------------------------------------------------------------
extern "C" void kernel_launch(void* const* d_in, const int* in_sizes, int n_in,
                              void* d_out, int out_size, void* d_ws, size_t ws_size,
                              hipStream_t stream)
{
    const float* x     = (const float*)d_in[0];
    const float* cosb  = (const float*)d_in[1];
    const float* sinb  = (const float*)d_in[2];
    const float* w_qkv = (const float*)d_in[3];
    const float* w_out = (const float*)d_in[4];
    float* out = (float*)d_out;

    constexpr size_t MB = 1u << 20;
    char* ws = (char*)d_ws;
    ushort_t* qb  = (ushort_t*)(ws);
    ushort_t* kb  = (ushort_t*)(ws + 8 * MB);
    ushort_t* vt  = (ushort_t*)(ws + 16 * MB);
    ushort_t* wob = (ushort_t*)(ws + 24 * MB);
    float*    lp  = (float*)   (ws + 26 * MB);
    float*    Op  = (float*)   (ws + 27 * MB);
    ushort_t* xb  = (ushort_t*)(ws + 27 * MB);   // aliases Op (disjoint lifetime)
    ushort_t* wqb = (ushort_t*)(ws + 35 * MB);   // aliases Op (disjoint lifetime)
    ushort_t* ob  = qb;                          // aliases qb (disjoint lifetime)

    prep<<<3072, 256, 0, stream>>>(x, w_qkv, w_out, xb, wqb, wob);
    gemm_qkv_mfma<<<dim3(24, 32), 256, 0, stream>>>(xb, wqb, qb, kb, vt, cosb, sinb);
    attn_mfma<<<dim3(16, 4, 16), 256, 0, stream>>>(qb, kb, vt, Op, lp);
    reduce_o<<<4096, 256, 0, stream>>>(Op, lp, ob);
    gemm_out_mfma<<<dim3(8, 32), 256, 0, stream>>>(ob, wob, out);
}

// Round 9
// 215.796 us; speedup vs baseline: 1.3515x; 1.3515x over previous
//
#include <hip/hip_runtime.h>
#include <hip/hip_bf16.h>

#define BATCH 2
#define SEQ   2048
#define DIM   1024
#define NH    16
#define HD    64
#define K_DIM 1024

typedef __attribute__((ext_vector_type(8))) short short8;
typedef __attribute__((ext_vector_type(4))) short short4v;
typedef __attribute__((ext_vector_type(4))) float f32x4;
typedef unsigned short ushort_t;

// fp32 -> bf16 bits, round-to-nearest-even
__device__ __forceinline__ unsigned short f2b(float x) {
    unsigned int u = __float_as_uint(x);
    u += 0x7FFFu + ((u >> 16) & 1u);
    return (unsigned short)(u >> 16);
}

// async global->LDS, 16B per lane; LDS dest = wave-uniform base + lane*16
#define ASYNC_COPY16(gp, lp) \
    __builtin_amdgcn_global_load_lds((const __attribute__((address_space(1))) void*)(gp), \
                                     (__attribute__((address_space(3))) void*)(lp), 16, 0, 0)

// ---------------------------------------------------------------------------
// Merged prep kernel: [0,1024) cast x; [1024,2560) transpose w_qkv;
// [2560,3072) transpose w_out.
// ---------------------------------------------------------------------------
__global__ __launch_bounds__(256)
void prep(const float* __restrict__ x, const float* __restrict__ w_qkv,
          const float* __restrict__ w_out, ushort_t* __restrict__ xb,
          ushort_t* __restrict__ wqb, ushort_t* __restrict__ wob)
{
    const int bid = blockIdx.x;
    if (bid < 1024) {
        constexpr int n4 = (BATCH * SEQ * DIM) / 4;
        int i = bid * 256 + threadIdx.x;
        for (; i < n4; i += 1024 * 256) {
            float4 v = ((const float4*)x)[i];
            short4v o;
            o[0] = (short)f2b(v.x); o[1] = (short)f2b(v.y);
            o[2] = (short)f2b(v.z); o[3] = (short)f2b(v.w);
            ((short4v*)xb)[i] = o;
        }
    } else {
        const int lane = threadIdx.x & 63;
        const float* src; ushort_t* dst; int N, job;
        if (bid < 2560) { src = w_qkv; dst = wqb; N = 3072; job = (bid - 1024) * 4 + (threadIdx.x >> 6); }
        else            { src = w_out; dst = wob; N = 1024; job = (bid - 2560) * 4 + (threadIdx.x >> 6); }
        const int jn = (N == 3072) ? (job % 48) : (job % 16);
        const int jk = (N == 3072) ? (job / 48) : (job / 16);
        const int n  = jn * 64 + lane;
        const int k0 = jk * 8;
        short8 o;
        #pragma unroll
        for (int j = 0; j < 8; ++j) o[j] = (short)f2b(src[(size_t)(k0 + j) * N + n]);
        *(short8*)(dst + (size_t)n * K_DIM + k0) = o;
    }
}

// ---------------------------------------------------------------------------
// MFMA GEMM mainloop (R5/m97-style, best measured): BK=64, single-buffered
// 16KB+16KB LDS, 2-barrier structure, chunk-XOR swizzle for conflict-free
// ds_read_b128.
// ---------------------------------------------------------------------------
__device__ __forceinline__ void mfma_gemm_tile(
    const ushort_t* __restrict__ Ag, const ushort_t* __restrict__ Bg,
    ushort_t* As, ushort_t* Bs, f32x4 acc[4][4])
{
    const int t = threadIdx.x;
    const int w = t >> 6, lane = t & 63;
    const int qd = lane >> 4, cl = lane & 15;
    const int srow = t >> 3;
    const int schunk = (t & 7) ^ (srow & 7);

    for (int k0 = 0; k0 < K_DIM; k0 += 64) {
        __syncthreads();
        #pragma unroll
        for (int j = 0; j < 4; ++j) {
            ASYNC_COPY16(Ag + (size_t)(j * 32 + srow) * K_DIM + k0 + schunk * 8,
                         As + (j * 32 + w * 8) * 64);
            ASYNC_COPY16(Bg + (size_t)(j * 32 + srow) * K_DIM + k0 + schunk * 8,
                         Bs + (j * 32 + w * 8) * 64);
        }
        __syncthreads();

        short8 af[4][2], bfr[4][2];
        #pragma unroll
        for (int rt = 0; rt < 4; ++rt) {
            const int row = (w >> 1) * 64 + rt * 16 + cl;
            #pragma unroll
            for (int kh = 0; kh < 2; ++kh)
                af[rt][kh] = *(const short8*)(As + row * 64 + (((kh * 4 + qd) ^ (row & 7)) * 8));
        }
        #pragma unroll
        for (int ct = 0; ct < 4; ++ct) {
            const int col = (w & 1) * 64 + ct * 16 + cl;
            #pragma unroll
            for (int kh = 0; kh < 2; ++kh)
                bfr[ct][kh] = *(const short8*)(Bs + col * 64 + (((kh * 4 + qd) ^ (col & 7)) * 8));
        }
        #pragma unroll
        for (int kh = 0; kh < 2; ++kh)
            #pragma unroll
            for (int rt = 0; rt < 4; ++rt)
                #pragma unroll
                for (int ct = 0; ct < 4; ++ct)
                    acc[rt][ct] = __builtin_amdgcn_mfma_f32_16x16x32_bf16(
                        af[rt][kh], bfr[ct][kh], acc[rt][ct], 0, 0, 0);
    }
}

// ---------------------------------------------------------------------------
// GEMM1: qkv = xb @ wqb^T with fused RoPE + bf16 stores.
// ---------------------------------------------------------------------------
__global__ __launch_bounds__(256)
void gemm_qkv_mfma(const ushort_t* __restrict__ xb, const ushort_t* __restrict__ wqb,
                   ushort_t* __restrict__ qb, ushort_t* __restrict__ kb,
                   ushort_t* __restrict__ vt,
                   const float* __restrict__ cosb, const float* __restrict__ sinb)
{
    __shared__ __align__(16) ushort_t As[128 * 64];
    __shared__ __align__(16) ushort_t Bs[128 * 64];
    const int m0 = blockIdx.y * 128, n0 = blockIdx.x * 128;

    f32x4 acc[4][4];
    #pragma unroll
    for (int i = 0; i < 4; ++i)
        #pragma unroll
        for (int j = 0; j < 4; ++j)
            #pragma unroll
            for (int r = 0; r < 4; ++r) acc[i][j][r] = 0.f;

    mfma_gemm_tile(xb + (size_t)m0 * K_DIM, wqb + (size_t)n0 * K_DIM, As, Bs, acc);

    const int t = threadIdx.x, w = t >> 6, lane = t & 63;
    const int qd = lane >> 4, cl = lane & 15;
    const int b = m0 >> 11;
    const int lbase = (m0 & 2047) + (w >> 1) * 64;
    const int region = blockIdx.x >> 3;              // 0=q, 1=k, 2=v
    const int h = (blockIdx.x & 7) * 2 + (w & 1);

    if (region < 2) {
        ushort_t* dst = region ? kb : qb;
        const float sc = region ? 1.0f : 0.18033688011111234f;  // 0.125*log2(e)
        #pragma unroll
        for (int rt = 0; rt < 4; ++rt) {
            #pragma unroll
            for (int r = 0; r < 4; ++r) {
                const int l = lbase + rt * 16 + qd * 4 + r;
                const float c0 = cosb[l * HD + cl],      s0 = sinb[l * HD + cl];
                const float c1 = cosb[l * HD + 16 + cl], s1 = sinb[l * HD + 16 + cl];
                const float v0 = acc[rt][0][r] * c0 - acc[rt][2][r] * s0;
                const float v1 = acc[rt][1][r] * c1 - acc[rt][3][r] * s1;
                const float v2 = acc[rt][2][r] * c0 + acc[rt][0][r] * s0;
                const float v3 = acc[rt][3][r] * c1 + acc[rt][1][r] * s1;
                ushort_t* p = dst + (((size_t)b * NH + h) * SEQ + l) * HD;
                p[cl]      = f2b(v0 * sc);
                p[16 + cl] = f2b(v1 * sc);
                p[32 + cl] = f2b(v2 * sc);
                p[48 + cl] = f2b(v3 * sc);
            }
        }
    } else {
        #pragma unroll
        for (int rt = 0; rt < 4; ++rt)
            #pragma unroll
            for (int ct = 0; ct < 4; ++ct) {
                const int d = ct * 16 + cl;
                const int l = lbase + rt * 16 + qd * 4;
                short4v o4;
                #pragma unroll
                for (int r = 0; r < 4; ++r) o4[r] = (short)f2b(acc[rt][ct][r]);
                *(short4v*)(vt + (((size_t)b * NH + h) * HD + d) * SEQ + l) = o4;
            }
    }
}

// ---------------------------------------------------------------------------
// GEMM2: out = ob @ wob^T, fp32 store.
// ---------------------------------------------------------------------------
__global__ __launch_bounds__(256)
void gemm_out_mfma(const ushort_t* __restrict__ ob, const ushort_t* __restrict__ wob,
                   float* __restrict__ out)
{
    __shared__ __align__(16) ushort_t As[128 * 64];
    __shared__ __align__(16) ushort_t Bs[128 * 64];
    const int m0 = blockIdx.y * 128, n0 = blockIdx.x * 128;

    f32x4 acc[4][4];
    #pragma unroll
    for (int i = 0; i < 4; ++i)
        #pragma unroll
        for (int j = 0; j < 4; ++j)
            #pragma unroll
            for (int r = 0; r < 4; ++r) acc[i][j][r] = 0.f;

    mfma_gemm_tile(ob + (size_t)m0 * K_DIM, wob + (size_t)n0 * K_DIM, As, Bs, acc);

    const int t = threadIdx.x, w = t >> 6, lane = t & 63;
    const int qd = lane >> 4, cl = lane & 15;
    const int mbase = m0 + (w >> 1) * 64, nbase = n0 + (w & 1) * 64;
    #pragma unroll
    for (int rt = 0; rt < 4; ++rt)
        #pragma unroll
        for (int ct = 0; ct < 4; ++ct)
            #pragma unroll
            for (int r = 0; r < 4; ++r)
                out[(size_t)(mbase + rt * 16 + qd * 4 + r) * DIM + nbase + ct * 16 + cl] =
                    acc[rt][ct][r];
}

// ---------------------------------------------------------------------------
// Flash attention (R6 known-good, 64.4us measured): split-K x2 (exact —
// no-max softmax partials are additive), XCD-local grid (h fastest), dbuf
// K/V LDS staging with post-barrier prefetch, PV-deferral one tile. 48KB LDS
// -> 3 blocks/CU, VGPR 84, no spill.
// ---------------------------------------------------------------------------
__global__ __launch_bounds__(256, 3)
void attn_mfma(const ushort_t* __restrict__ qb, const ushort_t* __restrict__ kb,
               const ushort_t* __restrict__ vt, float* __restrict__ Op,
               float* __restrict__ lp)
{
    const int h = blockIdx.x;                 // fastest -> K/V sharers on one XCD
    const int b = blockIdx.y >> 1;
    const int half = blockIdx.y & 1;
    const int qt = blockIdx.z;
    const int t = threadIdx.x;
    const int w = t >> 6, lane = t & 63;
    const int qd = lane >> 4, cl = lane & 15;
    constexpr int NT = SEQ / 64 / 2;          // 16 tiles per half

    __shared__ __align__(16) ushort_t Ks[2][64 * 64];
    __shared__ __align__(16) ushort_t Vs[2][64 * 64];
    __shared__ __align__(16) ushort_t P[4][2048];
    char* Pb = (char*)P[w];

    const size_t bh = (size_t)b * NH + h;
    const ushort_t* qbase = qb + (bh * SEQ + qt * 128 + w * 32) * HD;
    const ushort_t* kbase = kb + bh * SEQ * HD;
    const ushort_t* vbase = vt + bh * (size_t)HD * SEQ;

    const int p0 = w * 128 + lane;
    const int r0a = p0 >> 3,  c0a = (p0 & 7) ^ (r0a & 7);
    const int p1 = p0 + 64;
    const int r1a = p1 >> 3,  c1a = (p1 & 7) ^ (r1a & 7);
    const int ldsoff0 = (w * 128) * 8;
    const int ldsoff1 = (w * 128 + 64) * 8;

    short8 qf[2][2];
    #pragma unroll
    for (int nt = 0; nt < 2; ++nt)
        #pragma unroll
        for (int kh = 0; kh < 2; ++kh)
            qf[nt][kh] = *(const short8*)(qbase + (nt * 16 + cl) * HD + kh * 32 + qd * 8);

    f32x4 oaccT[4][2];
    float l_part[2] = {0.f, 0.f};
    #pragma unroll
    for (int dt = 0; dt < 4; ++dt)
        #pragma unroll
        for (int nt = 0; nt < 2; ++nt)
            #pragma unroll
            for (int r = 0; r < 4; ++r) oaccT[dt][nt][r] = 0.f;

    // deferred-PV state (zeros make the kt==0 PV a no-op)
    short8 pf_prev[2][2], vf_prev[4][2];
    #pragma unroll
    for (int nt = 0; nt < 2; ++nt)
        #pragma unroll
        for (int kh = 0; kh < 2; ++kh)
            #pragma unroll
            for (int e = 0; e < 8; ++e) pf_prev[nt][kh][e] = 0;
    #pragma unroll
    for (int dt = 0; dt < 4; ++dt)
        #pragma unroll
        for (int kh = 0; kh < 2; ++kh)
            #pragma unroll
            for (int e = 0; e < 8; ++e) vf_prev[dt][kh][e] = 0;

    const int g0 = half * NT;
    {   // stage tile g0 into buffer 0
        ASYNC_COPY16(kbase + (size_t)(g0 * 64 + r0a) * HD + c0a * 8, (ushort_t*)Ks[0] + ldsoff0);
        ASYNC_COPY16(kbase + (size_t)(g0 * 64 + r1a) * HD + c1a * 8, (ushort_t*)Ks[0] + ldsoff1);
        ASYNC_COPY16(vbase + (size_t)r0a * SEQ + g0 * 64 + c0a * 8,  (ushort_t*)Vs[0] + ldsoff0);
        ASYNC_COPY16(vbase + (size_t)r1a * SEQ + g0 * 64 + c1a * 8,  (ushort_t*)Vs[0] + ldsoff1);
    }

    for (int kt = 0; kt < NT; ++kt) {
        const int cur = kt & 1;
        __syncthreads();
        if (kt + 1 < NT) {
            const int g = g0 + kt + 1;
            ASYNC_COPY16(kbase + (size_t)(g * 64 + r0a) * HD + c0a * 8, (ushort_t*)Ks[cur ^ 1] + ldsoff0);
            ASYNC_COPY16(kbase + (size_t)(g * 64 + r1a) * HD + c1a * 8, (ushort_t*)Ks[cur ^ 1] + ldsoff1);
            ASYNC_COPY16(vbase + (size_t)r0a * SEQ + g * 64 + c0a * 8,  (ushort_t*)Vs[cur ^ 1] + ldsoff0);
            ASYNC_COPY16(vbase + (size_t)r1a * SEQ + g * 64 + c1a * 8,  (ushort_t*)Vs[cur ^ 1] + ldsoff1);
        }

        short8 kf[4][2], vf[4][2];
        #pragma unroll
        for (int mt = 0; mt < 4; ++mt)
            #pragma unroll
            for (int kh = 0; kh < 2; ++kh)
                kf[mt][kh] = *(const short8*)(Ks[cur] + ((mt * 16 + cl) * 8 + ((kh * 4 + qd) ^ (cl & 7))) * 8);
        #pragma unroll
        for (int dt = 0; dt < 4; ++dt)
            #pragma unroll
            for (int kh = 0; kh < 2; ++kh)
                vf[dt][kh] = *(const short8*)(Vs[cur] + ((dt * 16 + cl) * 8 + ((kh * 4 + qd) ^ (cl & 7))) * 8);

        // ---- S^T = K Q^T
        f32x4 s[4][2];
        #pragma unroll
        for (int mt = 0; mt < 4; ++mt)
            #pragma unroll
            for (int nt = 0; nt < 2; ++nt)
                #pragma unroll
                for (int r = 0; r < 4; ++r) s[mt][nt][r] = 0.f;
        #pragma unroll
        for (int kh = 0; kh < 2; ++kh)
            #pragma unroll
            for (int mt = 0; mt < 4; ++mt)
                #pragma unroll
                for (int nt = 0; nt < 2; ++nt)
                    s[mt][nt] = __builtin_amdgcn_mfma_f32_16x16x32_bf16(
                        kf[mt][kh], qf[nt][kh], s[mt][nt], 0, 0, 0);

        // ---- deferred O^T += V^T(kt-1) P^T(kt-1)  (registers only)
        #pragma unroll
        for (int kh = 0; kh < 2; ++kh)
            #pragma unroll
            for (int dt = 0; dt < 4; ++dt)
                #pragma unroll
                for (int nt = 0; nt < 2; ++nt)
                    oaccT[dt][nt] = __builtin_amdgcn_mfma_f32_16x16x32_bf16(
                        vf_prev[dt][kh], pf_prev[nt][kh], oaccT[dt][nt], 0, 0, 0);

        // ---- exp2 + pack + P^T write
        #pragma unroll
        for (int nt = 0; nt < 2; ++nt) {
            #pragma unroll
            for (int mt = 0; mt < 4; ++mt) {
                const float e0 = __builtin_amdgcn_exp2f(s[mt][nt][0]);
                const float e1 = __builtin_amdgcn_exp2f(s[mt][nt][1]);
                const float e2 = __builtin_amdgcn_exp2f(s[mt][nt][2]);
                const float e3 = __builtin_amdgcn_exp2f(s[mt][nt][3]);
                l_part[nt] += (e0 + e1) + (e2 + e3);
                union { __hip_bfloat162 h2[2]; unsigned long long u64; } pk;
                pk.h2[0] = __float22bfloat162_rn(make_float2(e0, e1));
                pk.h2[1] = __float22bfloat162_rn(make_float2(e2, e3));
                const int g = (mt * 2 + (qd >> 1)) ^ (cl & 7);
                *(unsigned long long*)(Pb + (nt * 16 + cl) * 128 + g * 16 + (qd & 1) * 8) = pk.u64;
            }
        }
        __builtin_amdgcn_wave_barrier();

        // ---- read P(kt) fragments for next iteration's deferred PV
        #pragma unroll
        for (int nt = 0; nt < 2; ++nt)
            #pragma unroll
            for (int kh = 0; kh < 2; ++kh)
                pf_prev[nt][kh] = *(const short8*)(Pb + (nt * 16 + cl) * 128 + (((kh * 4 + qd) ^ (cl & 7)) * 16));
        #pragma unroll
        for (int dt = 0; dt < 4; ++dt)
            #pragma unroll
            for (int kh = 0; kh < 2; ++kh)
                vf_prev[dt][kh] = vf[dt][kh];
    }

    // tail PV for the last tile
    #pragma unroll
    for (int kh = 0; kh < 2; ++kh)
        #pragma unroll
        for (int dt = 0; dt < 4; ++dt)
            #pragma unroll
            for (int nt = 0; nt < 2; ++nt)
                oaccT[dt][nt] = __builtin_amdgcn_mfma_f32_16x16x32_bf16(
                    vf_prev[dt][kh], pf_prev[nt][kh], oaccT[dt][nt], 0, 0, 0);

    // ---- epilogue: fp32 partials (no normalization)
    #pragma unroll
    for (int nt = 0; nt < 2; ++nt) {
        float l = l_part[nt];
        l += __shfl_xor(l, 16);
        l += __shfl_xor(l, 32);
        const int query = qt * 128 + w * 32 + nt * 16 + cl;
        if (qd == 0)
            lp[((size_t)half * BATCH + b) * NH * SEQ + (size_t)h * SEQ + query] = l;
        float* op = Op + (((size_t)half * BATCH + b) * SEQ + query) * DIM + h * HD;
        #pragma unroll
        for (int dt = 0; dt < 4; ++dt)
            *(f32x4*)(op + dt * 16 + qd * 4) = oaccT[dt][nt];
    }
}

// ---------------------------------------------------------------------------
// Combine split-K halves: ob = (Op0+Op1)/(lp0+lp1), bf16.
// ---------------------------------------------------------------------------
__global__ __launch_bounds__(256)
void reduce_o(const float* __restrict__ Op, const float* __restrict__ lp,
              ushort_t* __restrict__ ob)
{
    const int idx = blockIdx.x * 256 + threadIdx.x;
    const int d4 = idx & 255;
    const int l  = (idx >> 8) & 2047;
    const int b  = idx >> 19;
    const int h  = d4 >> 4;

    const size_t o_off = ((size_t)b * SEQ + l) * DIM + d4 * 4;
    const float4 a = *(const float4*)(Op + o_off);
    const float4 c = *(const float4*)(Op + (size_t)BATCH * SEQ * DIM + o_off);
    const size_t l_off = ((size_t)b * NH + h) * SEQ + l;
    const float inv = 1.0f / (lp[l_off] + lp[(size_t)BATCH * NH * SEQ + l_off]);

    short4v o4;
    o4[0] = (short)f2b((a.x + c.x) * inv);
    o4[1] = (short)f2b((a.y + c.y) * inv);
    o4[2] = (short)f2b((a.z + c.z) * inv);
    o4[3] = (short)f2b((a.w + c.w) * inv);
    *(short4v*)(ob + o_off) = o4;
}

// ---------------------------------------------------------------------------
extern "C" void kernel_launch(void* const* d_in, const int* in_sizes, int n_in,
                              void* d_out, int out_size, void* d_ws, size_t ws_size,
                              hipStream_t stream)
{
    const float* x     = (const float*)d_in[0];
    const float* cosb  = (const float*)d_in[1];
    const float* sinb  = (const float*)d_in[2];
    const float* w_qkv = (const float*)d_in[3];
    const float* w_out = (const float*)d_in[4];
    float* out = (float*)d_out;

    constexpr size_t MB = 1u << 20;
    char* ws = (char*)d_ws;
    ushort_t* qb  = (ushort_t*)(ws);
    ushort_t* kb  = (ushort_t*)(ws + 8 * MB);
    ushort_t* vt  = (ushort_t*)(ws + 16 * MB);
    ushort_t* wob = (ushort_t*)(ws + 24 * MB);
    float*    lp  = (float*)   (ws + 26 * MB);
    float*    Op  = (float*)   (ws + 27 * MB);
    ushort_t* xb  = (ushort_t*)(ws + 27 * MB);   // aliases Op (disjoint lifetime)
    ushort_t* wqb = (ushort_t*)(ws + 35 * MB);   // aliases Op (disjoint lifetime)
    ushort_t* ob  = qb;                          // aliases qb (disjoint lifetime)

    prep<<<3072, 256, 0, stream>>>(x, w_qkv, w_out, xb, wqb, wob);
    gemm_qkv_mfma<<<dim3(24, 32), 256, 0, stream>>>(xb, wqb, qb, kb, vt, cosb, sinb);
    attn_mfma<<<dim3(16, 4, 16), 256, 0, stream>>>(qb, kb, vt, Op, lp);
    reduce_o<<<4096, 256, 0, stream>>>(Op, lp, ob);
    gemm_out_mfma<<<dim3(8, 32), 256, 0, stream>>>(ob, wob, out);
}

// Round 10
// 208.274 us; speedup vs baseline: 1.4003x; 1.0361x over previous
//
#include <hip/hip_runtime.h>
#include <hip/hip_bf16.h>

#define BATCH 2
#define SEQ   2048
#define DIM   1024
#define NH    16
#define HD    64
#define K_DIM 1024

typedef __attribute__((ext_vector_type(8))) short short8;
typedef __attribute__((ext_vector_type(4))) short short4v;
typedef __attribute__((ext_vector_type(4))) float f32x4;
typedef unsigned short ushort_t;

// fp32 -> bf16 bits, round-to-nearest-even
__device__ __forceinline__ unsigned short f2b(float x) {
    unsigned int u = __float_as_uint(x);
    u += 0x7FFFu + ((u >> 16) & 1u);
    return (unsigned short)(u >> 16);
}

// async global->LDS, 16B per lane; LDS dest = wave-uniform base + lane*16
#define ASYNC_COPY16(gp, lp) \
    __builtin_amdgcn_global_load_lds((const __attribute__((address_space(1))) void*)(gp), \
                                     (__attribute__((address_space(3))) void*)(lp), 16, 0, 0)

// ---------------------------------------------------------------------------
// Merged prep kernel: [0,1024) cast x; [1024,2560) transpose w_qkv;
// [2560,3072) transpose w_out.
// ---------------------------------------------------------------------------
__global__ __launch_bounds__(256)
void prep(const float* __restrict__ x, const float* __restrict__ w_qkv,
          const float* __restrict__ w_out, ushort_t* __restrict__ xb,
          ushort_t* __restrict__ wqb, ushort_t* __restrict__ wob)
{
    const int bid = blockIdx.x;
    if (bid < 1024) {
        constexpr int n4 = (BATCH * SEQ * DIM) / 4;
        int i = bid * 256 + threadIdx.x;
        for (; i < n4; i += 1024 * 256) {
            float4 v = ((const float4*)x)[i];
            short4v o;
            o[0] = (short)f2b(v.x); o[1] = (short)f2b(v.y);
            o[2] = (short)f2b(v.z); o[3] = (short)f2b(v.w);
            ((short4v*)xb)[i] = o;
        }
    } else {
        const int lane = threadIdx.x & 63;
        const float* src; ushort_t* dst; int N, job;
        if (bid < 2560) { src = w_qkv; dst = wqb; N = 3072; job = (bid - 1024) * 4 + (threadIdx.x >> 6); }
        else            { src = w_out; dst = wob; N = 1024; job = (bid - 2560) * 4 + (threadIdx.x >> 6); }
        const int jn = (N == 3072) ? (job % 48) : (job % 16);
        const int jk = (N == 3072) ? (job / 48) : (job / 16);
        const int n  = jn * 64 + lane;
        const int k0 = jk * 8;
        short8 o;
        #pragma unroll
        for (int j = 0; j < 8; ++j) o[j] = (short)f2b(src[(size_t)(k0 + j) * N + n]);
        *(short8*)(dst + (size_t)n * K_DIM + k0) = o;
    }
}

// ---------------------------------------------------------------------------
// 128x128 MFMA GEMM mainloop (R6 measured-best): BK=32, double-buffered LDS
// (8KB/buf/matrix), post-barrier prefetch, chunk-XOR swizzle.
// ---------------------------------------------------------------------------
__device__ __forceinline__ void gemm_stage(const ushort_t* __restrict__ Ag,
                                           const ushort_t* __restrict__ Bg,
                                           ushort_t* As, ushort_t* Bs,
                                           int k0, int w, int r0, int c0)
{
    ASYNC_COPY16(Ag + (size_t)r0 * K_DIM + k0 + c0 * 8,        As + w * 512);
    ASYNC_COPY16(Ag + (size_t)(64 + r0) * K_DIM + k0 + c0 * 8, As + w * 512 + 2048);
    ASYNC_COPY16(Bg + (size_t)r0 * K_DIM + k0 + c0 * 8,        Bs + w * 512);
    ASYNC_COPY16(Bg + (size_t)(64 + r0) * K_DIM + k0 + c0 * 8, Bs + w * 512 + 2048);
}

__device__ __forceinline__ void mfma_gemm_tile(
    const ushort_t* __restrict__ Ag, const ushort_t* __restrict__ Bg,
    ushort_t (&As)[2][128 * 32], ushort_t (&Bs)[2][128 * 32], f32x4 acc[4][4])
{
    const int t = threadIdx.x;
    const int w = t >> 6, lane = t & 63;
    const int qd = lane >> 4, cl = lane & 15;
    const int p0 = w * 64 + lane;
    const int r0 = p0 >> 2;
    const int c0 = (p0 & 3) ^ (r0 & 3);

    gemm_stage(Ag, Bg, As[0], Bs[0], 0, w, r0, c0);

    for (int kt = 0; kt < K_DIM / 32; ++kt) {
        const int cur = kt & 1;
        __syncthreads();
        if (kt + 1 < K_DIM / 32)
            gemm_stage(Ag, Bg, As[cur ^ 1], Bs[cur ^ 1], (kt + 1) * 32, w, r0, c0);

        short8 af[4], bfr[4];
        #pragma unroll
        for (int rt = 0; rt < 4; ++rt) {
            const int row = (w >> 1) * 64 + rt * 16 + cl;
            af[rt] = *(const short8*)(As[cur] + row * 32 + ((qd ^ (row & 3)) * 8));
        }
        #pragma unroll
        for (int ct = 0; ct < 4; ++ct) {
            const int col = (w & 1) * 64 + ct * 16 + cl;
            bfr[ct] = *(const short8*)(Bs[cur] + col * 32 + ((qd ^ (col & 3)) * 8));
        }
        #pragma unroll
        for (int rt = 0; rt < 4; ++rt)
            #pragma unroll
            for (int ct = 0; ct < 4; ++ct)
                acc[rt][ct] = __builtin_amdgcn_mfma_f32_16x16x32_bf16(
                    af[rt], bfr[ct], acc[rt][ct], 0, 0, 0);
    }
}

// ---------------------------------------------------------------------------
// GEMM1: qkv = xb @ wqb^T with fused RoPE + bf16 stores.
// q/k stored with shared d-permutation d' = cl*4 + ct (S-dot invariant since
// both q and k use it) -> each lane writes one contiguous short4v per row.
// ---------------------------------------------------------------------------
__global__ __launch_bounds__(256, 3)
void gemm_qkv_mfma(const ushort_t* __restrict__ xb, const ushort_t* __restrict__ wqb,
                   ushort_t* __restrict__ qb, ushort_t* __restrict__ kb,
                   ushort_t* __restrict__ vt,
                   const float* __restrict__ cosb, const float* __restrict__ sinb)
{
    __shared__ __align__(16) ushort_t As[2][128 * 32];
    __shared__ __align__(16) ushort_t Bs[2][128 * 32];
    const int m0 = blockIdx.y * 128, n0 = blockIdx.x * 128;

    f32x4 acc[4][4];
    #pragma unroll
    for (int i = 0; i < 4; ++i)
        #pragma unroll
        for (int j = 0; j < 4; ++j)
            #pragma unroll
            for (int r = 0; r < 4; ++r) acc[i][j][r] = 0.f;

    mfma_gemm_tile(xb + (size_t)m0 * K_DIM, wqb + (size_t)n0 * K_DIM, As, Bs, acc);

    const int t = threadIdx.x, w = t >> 6, lane = t & 63;
    const int qd = lane >> 4, cl = lane & 15;
    const int b = m0 >> 11;
    const int lbase = (m0 & 2047) + (w >> 1) * 64;
    const int region = blockIdx.x >> 3;              // 0=q, 1=k, 2=v
    const int h = (blockIdx.x & 7) * 2 + (w & 1);

    if (region < 2) {
        ushort_t* dst = region ? kb : qb;
        const float sc = region ? 1.0f : 0.18033688011111234f;  // 0.125*log2(e)
        #pragma unroll
        for (int rt = 0; rt < 4; ++rt) {
            #pragma unroll
            for (int r = 0; r < 4; ++r) {
                const int l = lbase + rt * 16 + qd * 4 + r;
                const float c0 = cosb[l * HD + cl],      s0 = sinb[l * HD + cl];
                const float c1 = cosb[l * HD + 16 + cl], s1 = sinb[l * HD + 16 + cl];
                const float v0 = acc[rt][0][r] * c0 - acc[rt][2][r] * s0;
                const float v1 = acc[rt][1][r] * c1 - acc[rt][3][r] * s1;
                const float v2 = acc[rt][2][r] * c0 + acc[rt][0][r] * s0;
                const float v3 = acc[rt][3][r] * c1 + acc[rt][1][r] * s1;
                short4v o4;
                o4[0] = (short)f2b(v0 * sc);
                o4[1] = (short)f2b(v1 * sc);
                o4[2] = (short)f2b(v2 * sc);
                o4[3] = (short)f2b(v3 * sc);
                *(short4v*)(dst + (((size_t)b * NH + h) * SEQ + l) * HD + cl * 4) = o4;
            }
        }
    } else {
        #pragma unroll
        for (int rt = 0; rt < 4; ++rt)
            #pragma unroll
            for (int ct = 0; ct < 4; ++ct) {
                const int d = ct * 16 + cl;
                const int l = lbase + rt * 16 + qd * 4;
                short4v o4;
                #pragma unroll
                for (int r = 0; r < 4; ++r) o4[r] = (short)f2b(acc[rt][ct][r]);
                *(short4v*)(vt + (((size_t)b * NH + h) * HD + d) * SEQ + l) = o4;
            }
    }
}

// ---------------------------------------------------------------------------
// GEMM2: out = ob @ wob^T, 128x64 tiles (512 blocks -> 2 blocks/CU), BK=32
// dbuf staging, fp32 store. Waves 2x2 over (64m x 32n).
// ---------------------------------------------------------------------------
__device__ __forceinline__ void go_stage(const ushort_t* __restrict__ Ag,
                                         const ushort_t* __restrict__ Bg,
                                         ushort_t* As, ushort_t* Bs,
                                         int k0, int w, int lane)
{
    #pragma unroll
    for (int j = 0; j < 2; ++j) {
        const int r = w * 32 + j * 16 + (lane >> 2);
        const int c = (lane & 3) ^ (r & 3);
        ASYNC_COPY16(Ag + (size_t)r * K_DIM + k0 + c * 8, As + (w * 128 + j * 64) * 8);
    }
    const int rb = w * 16 + (lane >> 2);
    const int cb = (lane & 3) ^ (rb & 3);
    ASYNC_COPY16(Bg + (size_t)rb * K_DIM + k0 + cb * 8, Bs + (w * 64) * 8);
}

__global__ __launch_bounds__(256, 3)
void gemm_out_mfma(const ushort_t* __restrict__ ob, const ushort_t* __restrict__ wob,
                   float* __restrict__ out)
{
    __shared__ __align__(16) ushort_t As[2][128 * 32];
    __shared__ __align__(16) ushort_t Bs[2][64 * 32];
    const int m0 = blockIdx.y * 128, n0 = blockIdx.x * 64;
    const int t = threadIdx.x;
    const int w = t >> 6, lane = t & 63;
    const int qd = lane >> 4, cl = lane & 15;
    const int wr = w >> 1, wc = w & 1;

    f32x4 acc[4][2];
    #pragma unroll
    for (int i = 0; i < 4; ++i)
        #pragma unroll
        for (int j = 0; j < 2; ++j)
            #pragma unroll
            for (int r = 0; r < 4; ++r) acc[i][j][r] = 0.f;

    const ushort_t* Ag = ob  + (size_t)m0 * K_DIM;
    const ushort_t* Bg = wob + (size_t)n0 * K_DIM;
    go_stage(Ag, Bg, As[0], Bs[0], 0, w, lane);

    for (int kt = 0; kt < K_DIM / 32; ++kt) {
        const int cur = kt & 1;
        __syncthreads();
        if (kt + 1 < K_DIM / 32)
            go_stage(Ag, Bg, As[cur ^ 1], Bs[cur ^ 1], (kt + 1) * 32, w, lane);

        short8 af[4], bfr[2];
        #pragma unroll
        for (int rt = 0; rt < 4; ++rt) {
            const int row = wr * 64 + rt * 16 + cl;
            af[rt] = *(const short8*)(As[cur] + row * 32 + ((qd ^ (row & 3)) * 8));
        }
        #pragma unroll
        for (int ct = 0; ct < 2; ++ct) {
            const int col = wc * 32 + ct * 16 + cl;
            bfr[ct] = *(const short8*)(Bs[cur] + col * 32 + ((qd ^ (col & 3)) * 8));
        }
        #pragma unroll
        for (int rt = 0; rt < 4; ++rt)
            #pragma unroll
            for (int ct = 0; ct < 2; ++ct)
                acc[rt][ct] = __builtin_amdgcn_mfma_f32_16x16x32_bf16(
                    af[rt], bfr[ct], acc[rt][ct], 0, 0, 0);
    }

    const int mbase = m0 + wr * 64, nbase = n0 + wc * 32;
    #pragma unroll
    for (int rt = 0; rt < 4; ++rt)
        #pragma unroll
        for (int ct = 0; ct < 2; ++ct)
            #pragma unroll
            for (int r = 0; r < 4; ++r)
                out[(size_t)(mbase + rt * 16 + qd * 4 + r) * DIM + nbase + ct * 16 + cl] =
                    acc[rt][ct][r];
}

// ---------------------------------------------------------------------------
// Flash attention (R6/R9 known-good, ~62us measured): split-K x2, XCD-local
// grid, dbuf K/V staging, PV-deferral. 48KB LDS, VGPR 84, no spill.
// ---------------------------------------------------------------------------
__global__ __launch_bounds__(256, 3)
void attn_mfma(const ushort_t* __restrict__ qb, const ushort_t* __restrict__ kb,
               const ushort_t* __restrict__ vt, float* __restrict__ Op,
               float* __restrict__ lp)
{
    const int h = blockIdx.x;                 // fastest -> K/V sharers on one XCD
    const int b = blockIdx.y >> 1;
    const int half = blockIdx.y & 1;
    const int qt = blockIdx.z;
    const int t = threadIdx.x;
    const int w = t >> 6, lane = t & 63;
    const int qd = lane >> 4, cl = lane & 15;
    constexpr int NT = SEQ / 64 / 2;          // 16 tiles per half

    __shared__ __align__(16) ushort_t Ks[2][64 * 64];
    __shared__ __align__(16) ushort_t Vs[2][64 * 64];
    __shared__ __align__(16) ushort_t P[4][2048];
    char* Pb = (char*)P[w];

    const size_t bh = (size_t)b * NH + h;
    const ushort_t* qbase = qb + (bh * SEQ + qt * 128 + w * 32) * HD;
    const ushort_t* kbase = kb + bh * SEQ * HD;
    const ushort_t* vbase = vt + bh * (size_t)HD * SEQ;

    const int p0 = w * 128 + lane;
    const int r0a = p0 >> 3,  c0a = (p0 & 7) ^ (r0a & 7);
    const int p1 = p0 + 64;
    const int r1a = p1 >> 3,  c1a = (p1 & 7) ^ (r1a & 7);
    const int ldsoff0 = (w * 128) * 8;
    const int ldsoff1 = (w * 128 + 64) * 8;

    short8 qf[2][2];
    #pragma unroll
    for (int nt = 0; nt < 2; ++nt)
        #pragma unroll
        for (int kh = 0; kh < 2; ++kh)
            qf[nt][kh] = *(const short8*)(qbase + (nt * 16 + cl) * HD + kh * 32 + qd * 8);

    f32x4 oaccT[4][2];
    float l_part[2] = {0.f, 0.f};
    #pragma unroll
    for (int dt = 0; dt < 4; ++dt)
        #pragma unroll
        for (int nt = 0; nt < 2; ++nt)
            #pragma unroll
            for (int r = 0; r < 4; ++r) oaccT[dt][nt][r] = 0.f;

    // deferred-PV state (zeros make the kt==0 PV a no-op)
    short8 pf_prev[2][2], vf_prev[4][2];
    #pragma unroll
    for (int nt = 0; nt < 2; ++nt)
        #pragma unroll
        for (int kh = 0; kh < 2; ++kh)
            #pragma unroll
            for (int e = 0; e < 8; ++e) pf_prev[nt][kh][e] = 0;
    #pragma unroll
    for (int dt = 0; dt < 4; ++dt)
        #pragma unroll
        for (int kh = 0; kh < 2; ++kh)
            #pragma unroll
            for (int e = 0; e < 8; ++e) vf_prev[dt][kh][e] = 0;

    const int g0 = half * NT;
    {   // stage tile g0 into buffer 0
        ASYNC_COPY16(kbase + (size_t)(g0 * 64 + r0a) * HD + c0a * 8, (ushort_t*)Ks[0] + ldsoff0);
        ASYNC_COPY16(kbase + (size_t)(g0 * 64 + r1a) * HD + c1a * 8, (ushort_t*)Ks[0] + ldsoff1);
        ASYNC_COPY16(vbase + (size_t)r0a * SEQ + g0 * 64 + c0a * 8,  (ushort_t*)Vs[0] + ldsoff0);
        ASYNC_COPY16(vbase + (size_t)r1a * SEQ + g0 * 64 + c1a * 8,  (ushort_t*)Vs[0] + ldsoff1);
    }

    for (int kt = 0; kt < NT; ++kt) {
        const int cur = kt & 1;
        __syncthreads();
        if (kt + 1 < NT) {
            const int g = g0 + kt + 1;
            ASYNC_COPY16(kbase + (size_t)(g * 64 + r0a) * HD + c0a * 8, (ushort_t*)Ks[cur ^ 1] + ldsoff0);
            ASYNC_COPY16(kbase + (size_t)(g * 64 + r1a) * HD + c1a * 8, (ushort_t*)Ks[cur ^ 1] + ldsoff1);
            ASYNC_COPY16(vbase + (size_t)r0a * SEQ + g * 64 + c0a * 8,  (ushort_t*)Vs[cur ^ 1] + ldsoff0);
            ASYNC_COPY16(vbase + (size_t)r1a * SEQ + g * 64 + c1a * 8,  (ushort_t*)Vs[cur ^ 1] + ldsoff1);
        }

        short8 kf[4][2], vf[4][2];
        #pragma unroll
        for (int mt = 0; mt < 4; ++mt)
            #pragma unroll
            for (int kh = 0; kh < 2; ++kh)
                kf[mt][kh] = *(const short8*)(Ks[cur] + ((mt * 16 + cl) * 8 + ((kh * 4 + qd) ^ (cl & 7))) * 8);
        #pragma unroll
        for (int dt = 0; dt < 4; ++dt)
            #pragma unroll
            for (int kh = 0; kh < 2; ++kh)
                vf[dt][kh] = *(const short8*)(Vs[cur] + ((dt * 16 + cl) * 8 + ((kh * 4 + qd) ^ (cl & 7))) * 8);

        // ---- S^T = K Q^T
        f32x4 s[4][2];
        #pragma unroll
        for (int mt = 0; mt < 4; ++mt)
            #pragma unroll
            for (int nt = 0; nt < 2; ++nt)
                #pragma unroll
                for (int r = 0; r < 4; ++r) s[mt][nt][r] = 0.f;
        #pragma unroll
        for (int kh = 0; kh < 2; ++kh)
            #pragma unroll
            for (int mt = 0; mt < 4; ++mt)
                #pragma unroll
                for (int nt = 0; nt < 2; ++nt)
                    s[mt][nt] = __builtin_amdgcn_mfma_f32_16x16x32_bf16(
                        kf[mt][kh], qf[nt][kh], s[mt][nt], 0, 0, 0);

        // ---- deferred O^T += V^T(kt-1) P^T(kt-1)  (registers only)
        #pragma unroll
        for (int kh = 0; kh < 2; ++kh)
            #pragma unroll
            for (int dt = 0; dt < 4; ++dt)
                #pragma unroll
                for (int nt = 0; nt < 2; ++nt)
                    oaccT[dt][nt] = __builtin_amdgcn_mfma_f32_16x16x32_bf16(
                        vf_prev[dt][kh], pf_prev[nt][kh], oaccT[dt][nt], 0, 0, 0);

        // ---- exp2 + pack + P^T write
        #pragma unroll
        for (int nt = 0; nt < 2; ++nt) {
            #pragma unroll
            for (int mt = 0; mt < 4; ++mt) {
                const float e0 = __builtin_amdgcn_exp2f(s[mt][nt][0]);
                const float e1 = __builtin_amdgcn_exp2f(s[mt][nt][1]);
                const float e2 = __builtin_amdgcn_exp2f(s[mt][nt][2]);
                const float e3 = __builtin_amdgcn_exp2f(s[mt][nt][3]);
                l_part[nt] += (e0 + e1) + (e2 + e3);
                union { __hip_bfloat162 h2[2]; unsigned long long u64; } pk;
                pk.h2[0] = __float22bfloat162_rn(make_float2(e0, e1));
                pk.h2[1] = __float22bfloat162_rn(make_float2(e2, e3));
                const int g = (mt * 2 + (qd >> 1)) ^ (cl & 7);
                *(unsigned long long*)(Pb + (nt * 16 + cl) * 128 + g * 16 + (qd & 1) * 8) = pk.u64;
            }
        }
        __builtin_amdgcn_wave_barrier();

        // ---- read P(kt) fragments for next iteration's deferred PV
        #pragma unroll
        for (int nt = 0; nt < 2; ++nt)
            #pragma unroll
            for (int kh = 0; kh < 2; ++kh)
                pf_prev[nt][kh] = *(const short8*)(Pb + (nt * 16 + cl) * 128 + (((kh * 4 + qd) ^ (cl & 7)) * 16));
        #pragma unroll
        for (int dt = 0; dt < 4; ++dt)
            #pragma unroll
            for (int kh = 0; kh < 2; ++kh)
                vf_prev[dt][kh] = vf[dt][kh];
    }

    // tail PV for the last tile
    #pragma unroll
    for (int kh = 0; kh < 2; ++kh)
        #pragma unroll
        for (int dt = 0; dt < 4; ++dt)
            #pragma unroll
            for (int nt = 0; nt < 2; ++nt)
                oaccT[dt][nt] = __builtin_amdgcn_mfma_f32_16x16x32_bf16(
                    vf_prev[dt][kh], pf_prev[nt][kh], oaccT[dt][nt], 0, 0, 0);

    // ---- epilogue: fp32 partials (no normalization)
    #pragma unroll
    for (int nt = 0; nt < 2; ++nt) {
        float l = l_part[nt];
        l += __shfl_xor(l, 16);
        l += __shfl_xor(l, 32);
        const int query = qt * 128 + w * 32 + nt * 16 + cl;
        if (qd == 0)
            lp[((size_t)half * BATCH + b) * NH * SEQ + (size_t)h * SEQ + query] = l;
        float* op = Op + (((size_t)half * BATCH + b) * SEQ + query) * DIM + h * HD;
        #pragma unroll
        for (int dt = 0; dt < 4; ++dt)
            *(f32x4*)(op + dt * 16 + qd * 4) = oaccT[dt][nt];
    }
}

// ---------------------------------------------------------------------------
// Combine split-K halves: ob = (Op0+Op1)/(lp0+lp1), bf16.
// ---------------------------------------------------------------------------
__global__ __launch_bounds__(256)
void reduce_o(const float* __restrict__ Op, const float* __restrict__ lp,
              ushort_t* __restrict__ ob)
{
    const int idx = blockIdx.x * 256 + threadIdx.x;
    const int d4 = idx & 255;
    const int l  = (idx >> 8) & 2047;
    const int b  = idx >> 19;
    const int h  = d4 >> 4;

    const size_t o_off = ((size_t)b * SEQ + l) * DIM + d4 * 4;
    const float4 a = *(const float4*)(Op + o_off);
    const float4 c = *(const float4*)(Op + (size_t)BATCH * SEQ * DIM + o_off);
    const size_t l_off = ((size_t)b * NH + h) * SEQ + l;
    const float inv = 1.0f / (lp[l_off] + lp[(size_t)BATCH * NH * SEQ + l_off]);

    short4v o4;
    o4[0] = (short)f2b((a.x + c.x) * inv);
    o4[1] = (short)f2b((a.y + c.y) * inv);
    o4[2] = (short)f2b((a.z + c.z) * inv);
    o4[3] = (short)f2b((a.w + c.w) * inv);
    *(short4v*)(ob + o_off) = o4;
}

// ---------------------------------------------------------------------------
extern "C" void kernel_launch(void* const* d_in, const int* in_sizes, int n_in,
                              void* d_out, int out_size, void* d_ws, size_t ws_size,
                              hipStream_t stream)
{
    const float* x     = (const float*)d_in[0];
    const float* cosb  = (const float*)d_in[1];
    const float* sinb  = (const float*)d_in[2];
    const float* w_qkv = (const float*)d_in[3];
    const float* w_out = (const float*)d_in[4];
    float* out = (float*)d_out;

    constexpr size_t MB = 1u << 20;
    char* ws = (char*)d_ws;
    ushort_t* qb  = (ushort_t*)(ws);
    ushort_t* kb  = (ushort_t*)(ws + 8 * MB);
    ushort_t* vt  = (ushort_t*)(ws + 16 * MB);
    ushort_t* wob = (ushort_t*)(ws + 24 * MB);
    float*    lp  = (float*)   (ws + 26 * MB);
    float*    Op  = (float*)   (ws + 27 * MB);
    ushort_t* xb  = (ushort_t*)(ws + 27 * MB);   // aliases Op (disjoint lifetime)
    ushort_t* wqb = (ushort_t*)(ws + 35 * MB);   // aliases Op (disjoint lifetime)
    ushort_t* ob  = qb;                          // aliases qb (disjoint lifetime)

    prep<<<3072, 256, 0, stream>>>(x, w_qkv, w_out, xb, wqb, wob);
    gemm_qkv_mfma<<<dim3(24, 32), 256, 0, stream>>>(xb, wqb, qb, kb, vt, cosb, sinb);
    attn_mfma<<<dim3(16, 4, 16), 256, 0, stream>>>(qb, kb, vt, Op, lp);
    reduce_o<<<4096, 256, 0, stream>>>(Op, lp, ob);
    gemm_out_mfma<<<dim3(16, 32), 256, 0, stream>>>(ob, wob, out);
}

// Round 11
// 205.358 us; speedup vs baseline: 1.4202x; 1.0142x over previous
//
#include <hip/hip_runtime.h>
#include <hip/hip_bf16.h>

#define BATCH 2
#define SEQ   2048
#define DIM   1024
#define NH    16
#define HD    64
#define K_DIM 1024

typedef __attribute__((ext_vector_type(8))) short short8;
typedef __attribute__((ext_vector_type(4))) short short4v;
typedef __attribute__((ext_vector_type(4))) float f32x4;
typedef unsigned short ushort_t;

// fp32 -> bf16 bits, round-to-nearest-even
__device__ __forceinline__ unsigned short f2b(float x) {
    unsigned int u = __float_as_uint(x);
    u += 0x7FFFu + ((u >> 16) & 1u);
    return (unsigned short)(u >> 16);
}

// async global->LDS, 16B per lane; LDS dest = wave-uniform base + lane*16
#define ASYNC_COPY16(gp, lp) \
    __builtin_amdgcn_global_load_lds((const __attribute__((address_space(1))) void*)(gp), \
                                     (__attribute__((address_space(3))) void*)(lp), 16, 0, 0)

// ---------------------------------------------------------------------------
// Merged prep kernel: [0,1024) cast x; [1024,2560) transpose w_qkv;
// [2560,3072) transpose w_out.
// ---------------------------------------------------------------------------
__global__ __launch_bounds__(256)
void prep(const float* __restrict__ x, const float* __restrict__ w_qkv,
          const float* __restrict__ w_out, ushort_t* __restrict__ xb,
          ushort_t* __restrict__ wqb, ushort_t* __restrict__ wob)
{
    const int bid = blockIdx.x;
    if (bid < 1024) {
        constexpr int n4 = (BATCH * SEQ * DIM) / 4;
        int i = bid * 256 + threadIdx.x;
        for (; i < n4; i += 1024 * 256) {
            float4 v = ((const float4*)x)[i];
            short4v o;
            o[0] = (short)f2b(v.x); o[1] = (short)f2b(v.y);
            o[2] = (short)f2b(v.z); o[3] = (short)f2b(v.w);
            ((short4v*)xb)[i] = o;
        }
    } else {
        const int lane = threadIdx.x & 63;
        const float* src; ushort_t* dst; int N, job;
        if (bid < 2560) { src = w_qkv; dst = wqb; N = 3072; job = (bid - 1024) * 4 + (threadIdx.x >> 6); }
        else            { src = w_out; dst = wob; N = 1024; job = (bid - 2560) * 4 + (threadIdx.x >> 6); }
        const int jn = (N == 3072) ? (job % 48) : (job % 16);
        const int jk = (N == 3072) ? (job / 48) : (job / 16);
        const int n  = jn * 64 + lane;
        const int k0 = jk * 8;
        short8 o;
        #pragma unroll
        for (int j = 0; j < 8; ++j) o[j] = (short)f2b(src[(size_t)(k0 + j) * N + n]);
        *(short8*)(dst + (size_t)n * K_DIM + k0) = o;
    }
}

// ---------------------------------------------------------------------------
// 128x128 MFMA GEMM mainloop (R6 measured-best): BK=32, double-buffered LDS
// (8KB/buf/matrix), post-barrier prefetch, chunk-XOR swizzle.
// ---------------------------------------------------------------------------
__device__ __forceinline__ void gemm_stage(const ushort_t* __restrict__ Ag,
                                           const ushort_t* __restrict__ Bg,
                                           ushort_t* As, ushort_t* Bs,
                                           int k0, int w, int r0, int c0)
{
    ASYNC_COPY16(Ag + (size_t)r0 * K_DIM + k0 + c0 * 8,        As + w * 512);
    ASYNC_COPY16(Ag + (size_t)(64 + r0) * K_DIM + k0 + c0 * 8, As + w * 512 + 2048);
    ASYNC_COPY16(Bg + (size_t)r0 * K_DIM + k0 + c0 * 8,        Bs + w * 512);
    ASYNC_COPY16(Bg + (size_t)(64 + r0) * K_DIM + k0 + c0 * 8, Bs + w * 512 + 2048);
}

__device__ __forceinline__ void mfma_gemm_tile(
    const ushort_t* __restrict__ Ag, const ushort_t* __restrict__ Bg,
    ushort_t (&As)[2][128 * 32], ushort_t (&Bs)[2][128 * 32], f32x4 acc[4][4])
{
    const int t = threadIdx.x;
    const int w = t >> 6, lane = t & 63;
    const int qd = lane >> 4, cl = lane & 15;
    const int p0 = w * 64 + lane;
    const int r0 = p0 >> 2;
    const int c0 = (p0 & 3) ^ (r0 & 3);

    gemm_stage(Ag, Bg, As[0], Bs[0], 0, w, r0, c0);

    for (int kt = 0; kt < K_DIM / 32; ++kt) {
        const int cur = kt & 1;
        __syncthreads();
        if (kt + 1 < K_DIM / 32)
            gemm_stage(Ag, Bg, As[cur ^ 1], Bs[cur ^ 1], (kt + 1) * 32, w, r0, c0);

        short8 af[4], bfr[4];
        #pragma unroll
        for (int rt = 0; rt < 4; ++rt) {
            const int row = (w >> 1) * 64 + rt * 16 + cl;
            af[rt] = *(const short8*)(As[cur] + row * 32 + ((qd ^ (row & 3)) * 8));
        }
        #pragma unroll
        for (int ct = 0; ct < 4; ++ct) {
            const int col = (w & 1) * 64 + ct * 16 + cl;
            bfr[ct] = *(const short8*)(Bs[cur] + col * 32 + ((qd ^ (col & 3)) * 8));
        }
        #pragma unroll
        for (int rt = 0; rt < 4; ++rt)
            #pragma unroll
            for (int ct = 0; ct < 4; ++ct)
                acc[rt][ct] = __builtin_amdgcn_mfma_f32_16x16x32_bf16(
                    af[rt], bfr[ct], acc[rt][ct], 0, 0, 0);
    }
}

// ---------------------------------------------------------------------------
// GEMM1: qkv = xb @ wqb^T with fused RoPE + bf16 stores (d' = cl*4+ct perm).
// ---------------------------------------------------------------------------
__global__ __launch_bounds__(256, 3)
void gemm_qkv_mfma(const ushort_t* __restrict__ xb, const ushort_t* __restrict__ wqb,
                   ushort_t* __restrict__ qb, ushort_t* __restrict__ kb,
                   ushort_t* __restrict__ vt,
                   const float* __restrict__ cosb, const float* __restrict__ sinb)
{
    __shared__ __align__(16) ushort_t As[2][128 * 32];
    __shared__ __align__(16) ushort_t Bs[2][128 * 32];
    const int m0 = blockIdx.y * 128, n0 = blockIdx.x * 128;

    f32x4 acc[4][4];
    #pragma unroll
    for (int i = 0; i < 4; ++i)
        #pragma unroll
        for (int j = 0; j < 4; ++j)
            #pragma unroll
            for (int r = 0; r < 4; ++r) acc[i][j][r] = 0.f;

    mfma_gemm_tile(xb + (size_t)m0 * K_DIM, wqb + (size_t)n0 * K_DIM, As, Bs, acc);

    const int t = threadIdx.x, w = t >> 6, lane = t & 63;
    const int qd = lane >> 4, cl = lane & 15;
    const int b = m0 >> 11;
    const int lbase = (m0 & 2047) + (w >> 1) * 64;
    const int region = blockIdx.x >> 3;              // 0=q, 1=k, 2=v
    const int h = (blockIdx.x & 7) * 2 + (w & 1);

    if (region < 2) {
        ushort_t* dst = region ? kb : qb;
        const float sc = region ? 1.0f : 0.18033688011111234f;  // 0.125*log2(e)
        #pragma unroll
        for (int rt = 0; rt < 4; ++rt) {
            #pragma unroll
            for (int r = 0; r < 4; ++r) {
                const int l = lbase + rt * 16 + qd * 4 + r;
                const float c0 = cosb[l * HD + cl],      s0 = sinb[l * HD + cl];
                const float c1 = cosb[l * HD + 16 + cl], s1 = sinb[l * HD + 16 + cl];
                const float v0 = acc[rt][0][r] * c0 - acc[rt][2][r] * s0;
                const float v1 = acc[rt][1][r] * c1 - acc[rt][3][r] * s1;
                const float v2 = acc[rt][2][r] * c0 + acc[rt][0][r] * s0;
                const float v3 = acc[rt][3][r] * c1 + acc[rt][1][r] * s1;
                short4v o4;
                o4[0] = (short)f2b(v0 * sc);
                o4[1] = (short)f2b(v1 * sc);
                o4[2] = (short)f2b(v2 * sc);
                o4[3] = (short)f2b(v3 * sc);
                *(short4v*)(dst + (((size_t)b * NH + h) * SEQ + l) * HD + cl * 4) = o4;
            }
        }
    } else {
        #pragma unroll
        for (int rt = 0; rt < 4; ++rt)
            #pragma unroll
            for (int ct = 0; ct < 4; ++ct) {
                const int d = ct * 16 + cl;
                const int l = lbase + rt * 16 + qd * 4;
                short4v o4;
                #pragma unroll
                for (int r = 0; r < 4; ++r) o4[r] = (short)f2b(acc[rt][ct][r]);
                *(short4v*)(vt + (((size_t)b * NH + h) * HD + d) * SEQ + l) = o4;
            }
    }
}

// ---------------------------------------------------------------------------
// GEMM2: out = ob @ wob^T, 128x64 tiles (512 blocks -> 2 blocks/CU), BK=32
// dbuf staging, fp32 store.
// ---------------------------------------------------------------------------
__device__ __forceinline__ void go_stage(const ushort_t* __restrict__ Ag,
                                         const ushort_t* __restrict__ Bg,
                                         ushort_t* As, ushort_t* Bs,
                                         int k0, int w, int lane)
{
    #pragma unroll
    for (int j = 0; j < 2; ++j) {
        const int r = w * 32 + j * 16 + (lane >> 2);
        const int c = (lane & 3) ^ (r & 3);
        ASYNC_COPY16(Ag + (size_t)r * K_DIM + k0 + c * 8, As + (w * 128 + j * 64) * 8);
    }
    const int rb = w * 16 + (lane >> 2);
    const int cb = (lane & 3) ^ (rb & 3);
    ASYNC_COPY16(Bg + (size_t)rb * K_DIM + k0 + cb * 8, Bs + (w * 64) * 8);
}

__global__ __launch_bounds__(256, 3)
void gemm_out_mfma(const ushort_t* __restrict__ ob, const ushort_t* __restrict__ wob,
                   float* __restrict__ out)
{
    __shared__ __align__(16) ushort_t As[2][128 * 32];
    __shared__ __align__(16) ushort_t Bs[2][64 * 32];
    const int m0 = blockIdx.y * 128, n0 = blockIdx.x * 64;
    const int t = threadIdx.x;
    const int w = t >> 6, lane = t & 63;
    const int qd = lane >> 4, cl = lane & 15;
    const int wr = w >> 1, wc = w & 1;

    f32x4 acc[4][2];
    #pragma unroll
    for (int i = 0; i < 4; ++i)
        #pragma unroll
        for (int j = 0; j < 2; ++j)
            #pragma unroll
            for (int r = 0; r < 4; ++r) acc[i][j][r] = 0.f;

    const ushort_t* Ag = ob  + (size_t)m0 * K_DIM;
    const ushort_t* Bg = wob + (size_t)n0 * K_DIM;
    go_stage(Ag, Bg, As[0], Bs[0], 0, w, lane);

    for (int kt = 0; kt < K_DIM / 32; ++kt) {
        const int cur = kt & 1;
        __syncthreads();
        if (kt + 1 < K_DIM / 32)
            go_stage(Ag, Bg, As[cur ^ 1], Bs[cur ^ 1], (kt + 1) * 32, w, lane);

        short8 af[4], bfr[2];
        #pragma unroll
        for (int rt = 0; rt < 4; ++rt) {
            const int row = wr * 64 + rt * 16 + cl;
            af[rt] = *(const short8*)(As[cur] + row * 32 + ((qd ^ (row & 3)) * 8));
        }
        #pragma unroll
        for (int ct = 0; ct < 2; ++ct) {
            const int col = wc * 32 + ct * 16 + cl;
            bfr[ct] = *(const short8*)(Bs[cur] + col * 32 + ((qd ^ (col & 3)) * 8));
        }
        #pragma unroll
        for (int rt = 0; rt < 4; ++rt)
            #pragma unroll
            for (int ct = 0; ct < 2; ++ct)
                acc[rt][ct] = __builtin_amdgcn_mfma_f32_16x16x32_bf16(
                    af[rt], bfr[ct], acc[rt][ct], 0, 0, 0);
    }

    const int mbase = m0 + wr * 64, nbase = n0 + wc * 32;
    #pragma unroll
    for (int rt = 0; rt < 4; ++rt)
        #pragma unroll
        for (int ct = 0; ct < 2; ++ct)
            #pragma unroll
            for (int r = 0; r < 4; ++r)
                out[(size_t)(mbase + rt * 16 + qd * 4 + r) * DIM + nbase + ct * 16 + cl] =
                    acc[rt][ct][r];
}

// ---------------------------------------------------------------------------
// Flash attention v7: full-K per block (no split-K, no reduce pass), XCD-local
// grid (h fastest, qt slowest -> 16 K/V-sharing blocks per (b,h) on one XCD),
// dbuf K/V staging with post-barrier prefetch, PV-deferral. Normalizes with
// the locally-complete l and writes bf16 ob directly. 48KB LDS, VGPR ~84.
// ---------------------------------------------------------------------------
__global__ __launch_bounds__(256, 3)
void attn_mfma(const ushort_t* __restrict__ qb, const ushort_t* __restrict__ kb,
               const ushort_t* __restrict__ vt, ushort_t* __restrict__ ob)
{
    const int h = blockIdx.x;                 // fastest -> K/V sharers on one XCD
    const int b = blockIdx.y;
    const int qt = blockIdx.z;
    const int t = threadIdx.x;
    const int w = t >> 6, lane = t & 63;
    const int qd = lane >> 4, cl = lane & 15;
    constexpr int NT = SEQ / 64;              // 32 tiles, full range

    __shared__ __align__(16) ushort_t Ks[2][64 * 64];
    __shared__ __align__(16) ushort_t Vs[2][64 * 64];
    __shared__ __align__(16) ushort_t P[4][2048];
    char* Pb = (char*)P[w];

    const size_t bh = (size_t)b * NH + h;
    const ushort_t* qbase = qb + (bh * SEQ + qt * 128 + w * 32) * HD;
    const ushort_t* kbase = kb + bh * SEQ * HD;
    const ushort_t* vbase = vt + bh * (size_t)HD * SEQ;

    const int p0 = w * 128 + lane;
    const int r0a = p0 >> 3,  c0a = (p0 & 7) ^ (r0a & 7);
    const int p1 = p0 + 64;
    const int r1a = p1 >> 3,  c1a = (p1 & 7) ^ (r1a & 7);
    const int ldsoff0 = (w * 128) * 8;
    const int ldsoff1 = (w * 128 + 64) * 8;

    short8 qf[2][2];
    #pragma unroll
    for (int nt = 0; nt < 2; ++nt)
        #pragma unroll
        for (int kh = 0; kh < 2; ++kh)
            qf[nt][kh] = *(const short8*)(qbase + (nt * 16 + cl) * HD + kh * 32 + qd * 8);

    f32x4 oaccT[4][2];
    float l_part[2] = {0.f, 0.f};
    #pragma unroll
    for (int dt = 0; dt < 4; ++dt)
        #pragma unroll
        for (int nt = 0; nt < 2; ++nt)
            #pragma unroll
            for (int r = 0; r < 4; ++r) oaccT[dt][nt][r] = 0.f;

    // deferred-PV state (zeros make the kt==0 PV a no-op)
    short8 pf_prev[2][2], vf_prev[4][2];
    #pragma unroll
    for (int nt = 0; nt < 2; ++nt)
        #pragma unroll
        for (int kh = 0; kh < 2; ++kh)
            #pragma unroll
            for (int e = 0; e < 8; ++e) pf_prev[nt][kh][e] = 0;
    #pragma unroll
    for (int dt = 0; dt < 4; ++dt)
        #pragma unroll
        for (int kh = 0; kh < 2; ++kh)
            #pragma unroll
            for (int e = 0; e < 8; ++e) vf_prev[dt][kh][e] = 0;

    {   // stage tile 0 into buffer 0
        ASYNC_COPY16(kbase + (size_t)r0a * HD + c0a * 8,            (ushort_t*)Ks[0] + ldsoff0);
        ASYNC_COPY16(kbase + (size_t)r1a * HD + c1a * 8,            (ushort_t*)Ks[0] + ldsoff1);
        ASYNC_COPY16(vbase + (size_t)r0a * SEQ + c0a * 8,           (ushort_t*)Vs[0] + ldsoff0);
        ASYNC_COPY16(vbase + (size_t)r1a * SEQ + c1a * 8,           (ushort_t*)Vs[0] + ldsoff1);
    }

    for (int kt = 0; kt < NT; ++kt) {
        const int cur = kt & 1;
        __syncthreads();
        if (kt + 1 < NT) {
            const int g = kt + 1;
            ASYNC_COPY16(kbase + (size_t)(g * 64 + r0a) * HD + c0a * 8, (ushort_t*)Ks[cur ^ 1] + ldsoff0);
            ASYNC_COPY16(kbase + (size_t)(g * 64 + r1a) * HD + c1a * 8, (ushort_t*)Ks[cur ^ 1] + ldsoff1);
            ASYNC_COPY16(vbase + (size_t)r0a * SEQ + g * 64 + c0a * 8,  (ushort_t*)Vs[cur ^ 1] + ldsoff0);
            ASYNC_COPY16(vbase + (size_t)r1a * SEQ + g * 64 + c1a * 8,  (ushort_t*)Vs[cur ^ 1] + ldsoff1);
        }

        short8 kf[4][2], vf[4][2];
        #pragma unroll
        for (int mt = 0; mt < 4; ++mt)
            #pragma unroll
            for (int kh = 0; kh < 2; ++kh)
                kf[mt][kh] = *(const short8*)(Ks[cur] + ((mt * 16 + cl) * 8 + ((kh * 4 + qd) ^ (cl & 7))) * 8);
        #pragma unroll
        for (int dt = 0; dt < 4; ++dt)
            #pragma unroll
            for (int kh = 0; kh < 2; ++kh)
                vf[dt][kh] = *(const short8*)(Vs[cur] + ((dt * 16 + cl) * 8 + ((kh * 4 + qd) ^ (cl & 7))) * 8);

        // ---- S^T = K Q^T
        f32x4 s[4][2];
        #pragma unroll
        for (int mt = 0; mt < 4; ++mt)
            #pragma unroll
            for (int nt = 0; nt < 2; ++nt)
                #pragma unroll
                for (int r = 0; r < 4; ++r) s[mt][nt][r] = 0.f;
        #pragma unroll
        for (int kh = 0; kh < 2; ++kh)
            #pragma unroll
            for (int mt = 0; mt < 4; ++mt)
                #pragma unroll
                for (int nt = 0; nt < 2; ++nt)
                    s[mt][nt] = __builtin_amdgcn_mfma_f32_16x16x32_bf16(
                        kf[mt][kh], qf[nt][kh], s[mt][nt], 0, 0, 0);

        // ---- deferred O^T += V^T(kt-1) P^T(kt-1)  (registers only)
        #pragma unroll
        for (int kh = 0; kh < 2; ++kh)
            #pragma unroll
            for (int dt = 0; dt < 4; ++dt)
                #pragma unroll
                for (int nt = 0; nt < 2; ++nt)
                    oaccT[dt][nt] = __builtin_amdgcn_mfma_f32_16x16x32_bf16(
                        vf_prev[dt][kh], pf_prev[nt][kh], oaccT[dt][nt], 0, 0, 0);

        // ---- exp2 + pack + P^T write
        #pragma unroll
        for (int nt = 0; nt < 2; ++nt) {
            #pragma unroll
            for (int mt = 0; mt < 4; ++mt) {
                const float e0 = __builtin_amdgcn_exp2f(s[mt][nt][0]);
                const float e1 = __builtin_amdgcn_exp2f(s[mt][nt][1]);
                const float e2 = __builtin_amdgcn_exp2f(s[mt][nt][2]);
                const float e3 = __builtin_amdgcn_exp2f(s[mt][nt][3]);
                l_part[nt] += (e0 + e1) + (e2 + e3);
                union { __hip_bfloat162 h2[2]; unsigned long long u64; } pk;
                pk.h2[0] = __float22bfloat162_rn(make_float2(e0, e1));
                pk.h2[1] = __float22bfloat162_rn(make_float2(e2, e3));
                const int g = (mt * 2 + (qd >> 1)) ^ (cl & 7);
                *(unsigned long long*)(Pb + (nt * 16 + cl) * 128 + g * 16 + (qd & 1) * 8) = pk.u64;
            }
        }
        __builtin_amdgcn_wave_barrier();

        // ---- read P(kt) fragments for next iteration's deferred PV
        #pragma unroll
        for (int nt = 0; nt < 2; ++nt)
            #pragma unroll
            for (int kh = 0; kh < 2; ++kh)
                pf_prev[nt][kh] = *(const short8*)(Pb + (nt * 16 + cl) * 128 + (((kh * 4 + qd) ^ (cl & 7)) * 16));
        #pragma unroll
        for (int dt = 0; dt < 4; ++dt)
            #pragma unroll
            for (int kh = 0; kh < 2; ++kh)
                vf_prev[dt][kh] = vf[dt][kh];
    }

    // tail PV for the last tile
    #pragma unroll
    for (int kh = 0; kh < 2; ++kh)
        #pragma unroll
        for (int dt = 0; dt < 4; ++dt)
            #pragma unroll
            for (int nt = 0; nt < 2; ++nt)
                oaccT[dt][nt] = __builtin_amdgcn_mfma_f32_16x16x32_bf16(
                    vf_prev[dt][kh], pf_prev[nt][kh], oaccT[dt][nt], 0, 0, 0);

    // ---- epilogue: complete l -> normalize -> bf16 ob[b][query][h*64+d]
    #pragma unroll
    for (int nt = 0; nt < 2; ++nt) {
        float l = l_part[nt];
        l += __shfl_xor(l, 16);
        l += __shfl_xor(l, 32);
        const float inv = 1.0f / l;
        const int query = qt * 128 + w * 32 + nt * 16 + cl;
        ushort_t* op = ob + ((size_t)b * SEQ + query) * DIM + h * HD;
        #pragma unroll
        for (int dt = 0; dt < 4; ++dt) {
            short4v o4;
            #pragma unroll
            for (int r = 0; r < 4; ++r) o4[r] = (short)f2b(oaccT[dt][nt][r] * inv);
            *(short4v*)(op + dt * 16 + qd * 4) = o4;
        }
    }
}

// ---------------------------------------------------------------------------
extern "C" void kernel_launch(void* const* d_in, const int* in_sizes, int n_in,
                              void* d_out, int out_size, void* d_ws, size_t ws_size,
                              hipStream_t stream)
{
    const float* x     = (const float*)d_in[0];
    const float* cosb  = (const float*)d_in[1];
    const float* sinb  = (const float*)d_in[2];
    const float* w_qkv = (const float*)d_in[3];
    const float* w_out = (const float*)d_in[4];
    float* out = (float*)d_out;

    // workspace layout (peak 48MB, no aliasing hazards):
    //  [0,8)   qb   [8,16) kb   [16,24) vt   [24,26) wob
    //  [26,34) ob   [34,42) xb  [42,48) wqb
    constexpr size_t MB = 1u << 20;
    char* ws = (char*)d_ws;
    ushort_t* qb  = (ushort_t*)(ws);
    ushort_t* kb  = (ushort_t*)(ws + 8 * MB);
    ushort_t* vt  = (ushort_t*)(ws + 16 * MB);
    ushort_t* wob = (ushort_t*)(ws + 24 * MB);
    ushort_t* ob  = (ushort_t*)(ws + 26 * MB);
    ushort_t* xb  = (ushort_t*)(ws + 34 * MB);
    ushort_t* wqb = (ushort_t*)(ws + 42 * MB);

    prep<<<3072, 256, 0, stream>>>(x, w_qkv, w_out, xb, wqb, wob);
    gemm_qkv_mfma<<<dim3(24, 32), 256, 0, stream>>>(xb, wqb, qb, kb, vt, cosb, sinb);
    attn_mfma<<<dim3(16, 2, 16), 256, 0, stream>>>(qb, kb, vt, ob);
    gemm_out_mfma<<<dim3(16, 32), 256, 0, stream>>>(ob, wob, out);
}